// Round 4
// baseline (170.695 us; speedup 1.0000x reference)
//
#include <hip/hip_runtime.h>
#include <hip/hip_bf16.h>

// Problem constants
#define BB 2
#define FDIM 2048
#define FH 64
#define FW 128
#define NPIX (FH*FW)        // 8192 pixels per (dom,b)
#define NC 19
#define SH 512
#define SW 1024

// Workspace layout (bytes). sq+cnt+sum need zeroing (atomic accumulation).
#define OFF_SQ    0                         // float sq[2][19]         = 152 B
#define OFF_CNT   152                       // uint  cnt[2][19]        = 152 B
#define OFF_SUM   512                       // float sum[2][19][2048]  = 311296 B
#define ZERO_BYTES 311808
#define OFF_LAB   311808                    // uchar labels[2][2][8192]= 32768 B
#define OFF_CENT  344576                    // float cent[19][2048]    = 155648 B
#define OFF_DOTS  500224                    // float dots[57]
#define OFF_ROW   500452                    // float row[19]

typedef __attribute__((ext_vector_type(8))) short short8v;   // 8 bf16 (4 VGPRs)
typedef __attribute__((ext_vector_type(4))) float f32x4;     // MFMA C/D

__device__ inline short f32_to_bf16_bits(float x) {
  __hip_bfloat16 h = __float2bfloat16(x);
  return *reinterpret_cast<short*>(&h);
}

// ---------------------------------------------------------------------------
// Kernel 1: labels via align_corners bilinear downsample + argmax over C.
// 4 lanes per output pixel (5/5/5/4 channels each), shfl_xor argmax merge
// with first-max (lowest class index) tie-break. Replicates jnp.linspace
// f32 arithmetic and the reference's mul/add association exactly.
// ---------------------------------------------------------------------------
__global__ __launch_bounds__(256) void labels_kernel(
    const float* __restrict__ sm_s, const float* __restrict__ sm_t,
    unsigned char* __restrict__ labels, unsigned int* __restrict__ cnt) {
  __shared__ unsigned int lcnt[NC];
  int tid = threadIdx.x;
  if (tid < NC) lcnt[tid] = 0u;
  __syncthreads();

  int g = blockIdx.x * 256 + tid;          // 0..131071
  int pixid = g >> 2;                      // 0..32767
  int sub = g & 3;
  int dom = pixid >> 14;                   // block-uniform (64 pixels/block)
  int rem = pixid & 16383;
  int b   = rem >> 13;
  int pix = rem & (NPIX - 1);
  int oy  = pix >> 7;
  int ox  = pix & (FW - 1);

  const float* sm = dom ? sm_t : sm_s;

  const float step_y = 511.0f / 63.0f;     // f32, same as jnp.linspace delta
  const float step_x = 1023.0f / 127.0f;
  float fy = __fmul_rn((float)oy, step_y);
  float fx = __fmul_rn((float)ox, step_x);
  int y0 = (int)floorf(fy); int y1 = min(y0 + 1, SH - 1);
  int x0 = (int)floorf(fx); int x1 = min(x0 + 1, SW - 1);
  float wy = __fsub_rn(fy, (float)y0);
  float wx = __fsub_rn(fx, (float)x0);
  float omwy = __fsub_rn(1.0f, wy);
  float omwx = __fsub_rn(1.0f, wx);

  const float* base = sm + (size_t)b * (NC * SH * SW);
  float best = -1.0f; int bestc = 127;
  for (int c = sub; c < NC; c += 4) {
    const float* p = base + (size_t)c * (SH * SW);
    float v00 = p[y0 * SW + x0];
    float v01 = p[y0 * SW + x1];
    float v10 = p[y1 * SW + x0];
    float v11 = p[y1 * SW + x1];
    float r0  = __fadd_rn(__fmul_rn(v00, omwy), __fmul_rn(v10, wy));
    float r1  = __fadd_rn(__fmul_rn(v01, omwy), __fmul_rn(v11, wy));
    float val = __fadd_rn(__fmul_rn(r0, omwx), __fmul_rn(r1, wx));
    if (val > best) { best = val; bestc = c; }   // strict > == first-max in subset
  }
  // merge 4-lane group (lanes of one pixel are consecutive)
#pragma unroll
  for (int off = 1; off <= 2; off <<= 1) {
    float ov = __shfl_xor(best, off, 64);
    int   oc = __shfl_xor(bestc, off, 64);
    if (ov > best || (ov == best && oc < bestc)) { best = ov; bestc = oc; }
  }
  if (sub == 0) {
    labels[pixid] = (unsigned char)bestc;
    atomicAdd(&lcnt[bestc], 1u);
  }
  __syncthreads();
  if (tid < NC) atomicAdd(&cnt[dom * NC + tid], lcnt[tid]);  // block is dom-uniform
}

// ---------------------------------------------------------------------------
// Kernel 2 (hot): segment-sum as MFMA matmul.
//   S[f,c]  = sum_p feat[f,p]  * onehot[p,c]
//   Q[f,c]  = sum_p feat[f,p]^2* onehot[p,c]   (reduced over f -> Sq[c])
// A = feat (bf16-rn), loaded straight from global in A-fragment order
// (lane: row = l&15, k = 8*(l>>4)+j -> 8 consecutive f32 = 2 dwordx4).
// B = onehot built in-registers from labels (exact in bf16).
// Grid: 32 f-groups x 4 (d,b) planes x 4 K-splits = 512 blocks, 4 waves each;
// wave owns 16 f-rows and 2048 pixels. Epilogue: f32 global atomics.
// ---------------------------------------------------------------------------
__global__ __launch_bounds__(256) void segsum_kernel(
    const float* __restrict__ feat_s, const float* __restrict__ feat_t,
    const unsigned char* __restrict__ labels,
    float* __restrict__ sum, float* __restrict__ sq) {
  int tid = threadIdx.x;
  int wv = tid >> 6, l = tid & 63;
  int m16 = l & 15, grp = l >> 4;

  int bid = blockIdx.x;
  int fg    = bid & 31;                    // f-group (64 f each)
  int plane = (bid >> 5) & 3;              // (d,b)
  int ks    = bid >> 7;                    // K-split 0..3 (2048 pix each)
  int d = plane >> 1, b = plane & 1;

  const float* feat = d ? feat_t : feat_s;
  int f_row = fg * 64 + wv * 16 + m16;     // A-fragment row for this lane
  const float* arow = feat + ((size_t)b * FDIM + f_row) * NPIX + ks * 2048;
  const unsigned char* labp = labels + (d * 2 + b) * NPIX + ks * 2048;

  f32x4 accS0 = {0.f,0.f,0.f,0.f}, accS1 = {0.f,0.f,0.f,0.f};
  f32x4 accQ0 = {0.f,0.f,0.f,0.f}, accQ1 = {0.f,0.f,0.f,0.f};

#pragma unroll 2
  for (int kt = 0; kt < 64; ++kt) {
    int k0 = kt * 32 + grp * 8;
    float4 v0 = *(const float4*)(arow + k0);
    float4 v1 = *(const float4*)(arow + k0 + 4);
    uint2 lw = *(const uint2*)(labp + k0);
    float vv0 = v0.x, vv1 = v0.y, vv2 = v0.z, vv3 = v0.w;
    float vv4 = v1.x, vv5 = v1.y, vv6 = v1.z, vv7 = v1.w;
    short8v a, a2, b0, b1;
#pragma unroll
    for (int j = 0; j < 8; ++j) {
      float x = (j==0)?vv0:(j==1)?vv1:(j==2)?vv2:(j==3)?vv3:(j==4)?vv4:(j==5)?vv5:(j==6)?vv6:vv7;
      a[j]  = f32_to_bf16_bits(x);
      a2[j] = f32_to_bf16_bits(x * x);
      unsigned lab = ((j < 4 ? lw.x : lw.y) >> ((j & 3) * 8)) & 0xFFu;
      b0[j] = (lab == (unsigned)m16)        ? (short)0x3F80 : (short)0;
      b1[j] = (lab == (unsigned)(m16 + 16)) ? (short)0x3F80 : (short)0;
    }
    accS0 = __builtin_amdgcn_mfma_f32_16x16x32_bf16(a,  b0, accS0, 0, 0, 0);
    accS1 = __builtin_amdgcn_mfma_f32_16x16x32_bf16(a,  b1, accS1, 0, 0, 0);
    accQ0 = __builtin_amdgcn_mfma_f32_16x16x32_bf16(a2, b0, accQ0, 0, 0, 0);
    accQ1 = __builtin_amdgcn_mfma_f32_16x16x32_bf16(a2, b1, accQ1, 0, 0, 0);
  }

  // C/D layout (verified): col = l&15 (= class), row = (l>>4)*4 + reg (= f).
  int c0 = l & 15;
  int fbw = fg * 64 + wv * 16 + (l >> 4) * 4;
  size_t sbase0 = ((size_t)d * NC + c0) * FDIM + fbw;
#pragma unroll
  for (int r = 0; r < 4; ++r) unsafeAtomicAdd(&sum[sbase0 + r], accS0[r]);
  if (c0 < 3) {
    size_t sbase1 = ((size_t)d * NC + 16 + c0) * FDIM + fbw;
#pragma unroll
    for (int r = 0; r < 4; ++r) unsafeAtomicAdd(&sum[sbase1 + r], accS1[r]);
  }
  // Sq: reduce Q over all 16 rows (4 regs + lanes l, l^16, l^32, l^48)
  float q0 = accQ0[0] + accQ0[1] + accQ0[2] + accQ0[3];
  float q1 = accQ1[0] + accQ1[1] + accQ1[2] + accQ1[3];
  q0 += __shfl_xor(q0, 16, 64); q0 += __shfl_xor(q0, 32, 64);
  q1 += __shfl_xor(q1, 16, 64); q1 += __shfl_xor(q1, 32, 64);
  if (l < 16) unsafeAtomicAdd(&sq[d * NC + l], q0);
  if (l < 3)  unsafeAtomicAdd(&sq[d * NC + 16 + l], q1);
}

// Block reduction helper (256 threads)
__device__ inline float block_reduce(float v, float* red, int tid) {
  red[tid] = v; __syncthreads();
  for (int s = 128; s > 0; s >>= 1) {
    if (tid < s) red[tid] += red[tid + s];
    __syncthreads();
  }
  float r = red[0];
  __syncthreads();
  return r;
}

// ---------------------------------------------------------------------------
// Kernel 3a: centroids[c][f] = (S_s + S_t)/max(cnt,1); also per-class
// dot_s = cent.S_s, dot_t = cent.S_t, cc = |cent|^2.
// ---------------------------------------------------------------------------
__global__ __launch_bounds__(256) void centroid_kernel(
    const float* __restrict__ sum, const unsigned int* __restrict__ cnt,
    float* __restrict__ cent, float* __restrict__ dots) {
  __shared__ float red[256];
  int c = blockIdx.x;
  int tid = threadIdx.x;
  float cs = (float)cnt[c];
  float ct = (float)cnt[NC + c];
  float denom = fmaxf(cs + ct, 1.0f);
  float ds = 0.f, dt = 0.f, cc = 0.f;
  for (int f = tid; f < FDIM; f += 256) {
    float ssv = sum[(size_t)c * FDIM + f];
    float stv = sum[(size_t)(NC + c) * FDIM + f];
    float cf = (ssv + stv) / denom;
    cent[(size_t)c * FDIM + f] = cf;
    ds += cf * ssv; dt += cf * stv; cc += cf * cf;
  }
  float rds = block_reduce(ds, red, tid);
  float rdt = block_reduce(dt, red, tid);
  float rcc = block_reduce(cc, red, tid);
  if (tid == 0) {
    dots[c] = rds;
    dots[NC + c] = rdt;
    dots[2 * NC + c] = rcc;
  }
}

// ---------------------------------------------------------------------------
// Kernel 3b: row[i] = sum_{j != i, seen i&j} sum_f (c_i - c_j)^2
// ---------------------------------------------------------------------------
__global__ __launch_bounds__(256) void pair_kernel(
    const float* __restrict__ cent, const unsigned int* __restrict__ cnt,
    float* __restrict__ row) {
  __shared__ float red[256];
  int i = blockIdx.x;
  int tid = threadIdx.x;
  bool seen_i = (cnt[i] + cnt[NC + i]) > 0u;
  float acc = 0.f;
  if (seen_i) {
    for (int j = 0; j < NC; ++j) {
      if (j == i) continue;
      if ((cnt[j] + cnt[NC + j]) == 0u) continue;
      for (int f = tid; f < FDIM; f += 256) {
        float dd = cent[(size_t)i * FDIM + f] - cent[(size_t)j * FDIM + f];
        acc += dd * dd;
      }
    }
  }
  float r = block_reduce(acc, red, tid);
  if (tid == 0) row[i] = r;
}

// ---------------------------------------------------------------------------
// Kernel 3c: assemble the 3 outputs (p == 2).
// ---------------------------------------------------------------------------
__global__ void final_kernel(
    const unsigned int* __restrict__ cnt, const float* __restrict__ sq,
    const float* __restrict__ dots, const float* __restrict__ row,
    float* __restrict__ out) {
  if (blockIdx.x != 0 || threadIdx.x != 0) return;
  const float fdim = (float)FDIM;
  int nseen = 0;
  for (int c = 0; c < NC; ++c)
    if (cnt[c] + cnt[NC + c] > 0u) nseen++;
  float nseenf = (float)nseen;

  float c_dist = 0.f, fs = 0.f, ft = 0.f;
  int nvs = 0, nvt = 0;
  for (int c = 0; c < NC; ++c) {
    float cs = (float)cnt[c];
    float ct = (float)cnt[NC + c];
    float cc = dots[2 * NC + c];
    if (cs > 0.f) {
      float ssq = sq[c] - 2.0f * dots[c] + cs * cc;
      ssq = fmaxf(ssq, 0.f);
      fs += sqrtf(ssq) / (cs * fdim);
      nvs++;
    }
    if (ct > 0.f) {
      float ssq = sq[NC + c] - 2.0f * dots[NC + c] + ct * cc;
      ssq = fmaxf(ssq, 0.f);
      ft += sqrtf(ssq) / (ct * fdim);
      nvt++;
    }
    if (cs + ct > 0.f) {
      c_dist += sqrtf(row[c]) / ((nseenf - 1.0f) * fdim);
    }
  }
  out[0] = c_dist / nseenf;
  out[1] = fs / (float)nvs;
  out[2] = ft / (float)nvt;
}

extern "C" void kernel_launch(void* const* d_in, const int* in_sizes, int n_in,
                              void* d_out, int out_size, void* d_ws, size_t ws_size,
                              hipStream_t stream) {
  const float* sfeat = (const float*)d_in[0];
  const float* ssm   = (const float*)d_in[1];
  const float* tfeat = (const float*)d_in[2];
  const float* tsm   = (const float*)d_in[3];
  float* out = (float*)d_out;

  char* ws = (char*)d_ws;
  float*         sq     = (float*)(ws + OFF_SQ);
  unsigned int*  cnt    = (unsigned int*)(ws + OFF_CNT);
  float*         sum    = (float*)(ws + OFF_SUM);
  unsigned char* labels = (unsigned char*)(ws + OFF_LAB);
  float*         cent   = (float*)(ws + OFF_CENT);
  float*         dots   = (float*)(ws + OFF_DOTS);
  float*         row    = (float*)(ws + OFF_ROW);

  // zero sq+cnt+sum (atomic accumulators; graph replays need re-zeroing)
  hipMemsetAsync(ws, 0, ZERO_BYTES, stream);

  labels_kernel  <<<512, 256, 0, stream>>>(ssm, tsm, labels, cnt);
  segsum_kernel  <<<512, 256, 0, stream>>>(sfeat, tfeat, labels, sum, sq);
  centroid_kernel<<<NC,  256, 0, stream>>>(sum, cnt, cent, dots);
  pair_kernel    <<<NC,  256, 0, stream>>>(cent, cnt, row);
  final_kernel   <<<1,   64,  0, stream>>>(cnt, sq, dots, row, out);
}